// Round 14
// baseline (2298.239 us; speedup 1.0000x reference)
//
#include <hip/hip_runtime.h>
#include <math.h>

#define G 5000
#define IN 64
#define D 128
#define E 240000
#define EG (E + G)
#define SLOPE 0.2f
#define GD (G * D)
#define NB_M 1250        // aggmlp blocks (4 dests each)
#define GPB2 10
#define NBX (G / GPB2)   // 500 xlxr tiles
#define NB_PG 1250       // pergene blocks
#define NB_H 240         // hist/bucket blocks (61440 int4 units >= 61250)

__device__ __forceinline__ float leaky(float v) { return v >= 0.f ? v : SLOPE * v; }

// ================= device bodies (shared by pipeline + rep kernels) =================

__device__ __forceinline__ void pergene_body(const float* __restrict__ x,
                                             const float* __restrict__ Win,
                                             const float* __restrict__ bin,
                                             float* __restrict__ h) {
    int g = (blockIdx.x * 256 + threadIdx.x) >> 6;
    int lane = threadIdx.x & 63;
    if (g >= G) return;
    float xv = x[g * IN + lane];
    const float* W = Win + (size_t)g * IN * D + lane * 2;
    float2 acc = *(const float2*)(bin + g * D + lane * 2);
#pragma unroll
    for (int i = 0; i < IN; ++i) {
        float xi = __shfl(xv, i);
        float2 w2 = *(const float2*)(W + (size_t)i * D);
        acc.x = fmaf(xi, w2.x, acc.x);
        acc.y = fmaf(xi, w2.y, acc.y);
    }
    float2 o = { fmaxf(acc.x, 0.f), fmaxf(acc.y, 0.f) };
    *(float2*)(h + g * D + lane * 2) = o;
}

__device__ __forceinline__ void xlxr_body(int bid,
                                          const float* __restrict__ h,
                                          const float* __restrict__ Wl,
                                          const float* __restrict__ bl,
                                          const float* __restrict__ Wr,
                                          const float* __restrict__ br,
                                          float* __restrict__ xl,
                                          float* __restrict__ xr) {
    int g0 = bid * GPB2;
    int wv = __builtin_amdgcn_readfirstlane(threadIdx.x >> 6);
    int half = wv >> 1;
    int sub  = wv & 1;
    int lane = threadIdx.x & 63;
    int d = lane * 2;
    const float* W = half ? Wr : Wl;
    const float* bb = half ? br : bl;
    float* o = half ? xr : xl;
    float2 bv = *(const float2*)(bb + d);
    float2 acc0 = bv, acc1 = bv, acc2 = bv, acc3 = bv, acc4 = bv;
    const float* hr = h + (size_t)(g0 + sub * 5) * D;
    for (int k4 = 0; k4 < 32; ++k4) {
        int k = k4 * 4;
        float2 w0 = *(const float2*)(W + (k + 0) * D + d);
        float2 w1 = *(const float2*)(W + (k + 1) * D + d);
        float2 w2 = *(const float2*)(W + (k + 2) * D + d);
        float2 w3 = *(const float2*)(W + (k + 3) * D + d);
        float4 h0 = *(const float4*)(hr + 0 * D + k);
        float4 h1 = *(const float4*)(hr + 1 * D + k);
        float4 h2 = *(const float4*)(hr + 2 * D + k);
        float4 h3 = *(const float4*)(hr + 3 * D + k);
        float4 h4 = *(const float4*)(hr + 4 * D + k);
        acc0.x = fmaf(h0.x, w0.x, acc0.x); acc0.y = fmaf(h0.x, w0.y, acc0.y);
        acc0.x = fmaf(h0.y, w1.x, acc0.x); acc0.y = fmaf(h0.y, w1.y, acc0.y);
        acc0.x = fmaf(h0.z, w2.x, acc0.x); acc0.y = fmaf(h0.z, w2.y, acc0.y);
        acc0.x = fmaf(h0.w, w3.x, acc0.x); acc0.y = fmaf(h0.w, w3.y, acc0.y);
        acc1.x = fmaf(h1.x, w0.x, acc1.x); acc1.y = fmaf(h1.x, w0.y, acc1.y);
        acc1.x = fmaf(h1.y, w1.x, acc1.x); acc1.y = fmaf(h1.y, w1.y, acc1.y);
        acc1.x = fmaf(h1.z, w2.x, acc1.x); acc1.y = fmaf(h1.z, w2.y, acc1.y);
        acc1.x = fmaf(h1.w, w3.x, acc1.x); acc1.y = fmaf(h1.w, w3.y, acc1.y);
        acc2.x = fmaf(h2.x, w0.x, acc2.x); acc2.y = fmaf(h2.x, w0.y, acc2.y);
        acc2.x = fmaf(h2.y, w1.x, acc2.x); acc2.y = fmaf(h2.y, w1.y, acc2.y);
        acc2.x = fmaf(h2.z, w2.x, acc2.x); acc2.y = fmaf(h2.z, w2.y, acc2.y);
        acc2.x = fmaf(h2.w, w3.x, acc2.x); acc2.y = fmaf(h2.w, w3.y, acc2.y);
        acc3.x = fmaf(h3.x, w0.x, acc3.x); acc3.y = fmaf(h3.x, w0.y, acc3.y);
        acc3.x = fmaf(h3.y, w1.x, acc3.x); acc3.y = fmaf(h3.y, w1.y, acc3.y);
        acc3.x = fmaf(h3.z, w2.x, acc3.x); acc3.y = fmaf(h3.z, w2.y, acc3.y);
        acc3.x = fmaf(h3.w, w3.x, acc3.x); acc3.y = fmaf(h3.w, w3.y, acc3.y);
        acc4.x = fmaf(h4.x, w0.x, acc4.x); acc4.y = fmaf(h4.x, w0.y, acc4.y);
        acc4.x = fmaf(h4.y, w1.x, acc4.x); acc4.y = fmaf(h4.y, w1.y, acc4.y);
        acc4.x = fmaf(h4.z, w2.x, acc4.x); acc4.y = fmaf(h4.z, w2.y, acc4.y);
        acc4.x = fmaf(h4.w, w3.x, acc4.x); acc4.y = fmaf(h4.w, w3.y, acc4.y);
    }
    int gbase = g0 + sub * 5;
    *(float2*)(o + (size_t)(gbase + 0) * D + d) = acc0;
    *(float2*)(o + (size_t)(gbase + 1) * D + d) = acc1;
    *(float2*)(o + (size_t)(gbase + 2) * D + d) = acc2;
    *(float2*)(o + (size_t)(gbase + 3) * D + d) = acc3;
    *(float2*)(o + (size_t)(gbase + 4) * D + d) = acc4;
}

__device__ __forceinline__ void scan_body(const int* __restrict__ cnt,
                                          int* __restrict__ rowptr,
                                          int* __restrict__ cursor,
                                          int* ssum) {
    int tid = threadIdx.x;
    const int CH = (G + 255) / 256;   // 20
    int base = tid * CH;
    int s = 0;
    for (int k = 0; k < CH; ++k) { int idx = base + k; if (idx < G) s += cnt[idx]; }
    ssum[tid] = s;
    __syncthreads();
    for (int off = 1; off < 256; off <<= 1) {
        int v = ssum[tid];
        int add = (tid >= off) ? ssum[tid - off] : 0;
        __syncthreads();
        ssum[tid] = v + add;
        __syncthreads();
    }
    int run = (tid == 0) ? 0 : ssum[tid - 1];
    for (int k = 0; k < CH; ++k) {
        int idx = base + k;
        if (idx < G) { rowptr[idx] = run; cursor[idx] = run; run += cnt[idx]; }
    }
    if (tid == 255) rowptr[G] = run;   // == EG
}

__device__ __forceinline__ void aggmlp_body(const int* __restrict__ rowptr,
                                            const int* __restrict__ ssrc,
                                            const float* __restrict__ xl,
                                            const float* __restrict__ xr,
                                            const float* __restrict__ att,
                                            const float* __restrict__ bias,
                                            const float* __restrict__ W1,
                                            float* __restrict__ partials,
                                            float (*w_lds)[64], int (*s_lds)[64],
                                            float2 (*red)[64]) {
    int wid = threadIdx.x >> 6;
    int lane = threadIdx.x & 63;
    int t = __builtin_amdgcn_readfirstlane(blockIdx.x * 4 + wid);
    const float* xrt = xr + (size_t)t * D;
    int lane2 = lane * 2;
    float2 acc = { 0.f, 0.f };
    float z = 0.f;
    int e0 = rowptr[t], e1 = rowptr[t + 1];
    for (int base = e0; base < e1; base += 64) {
        int nv = e1 - base; if (nv > 64) nv = 64;
        int mye = base + lane;
        int s = ssrc[mye < e1 ? mye : e1 - 1];
        const float* xls = xl + (size_t)s * D;
        float v0 = 0.f, v1 = 0.f;
#pragma unroll
        for (int dc = 0; dc < D; dc += 8) {
            float4 xa = *(const float4*)(xls + dc);
            float4 xb = *(const float4*)(xls + dc + 4);
            float4 ra = *(const float4*)(xrt + dc);
            float4 rb = *(const float4*)(xrt + dc + 4);
            float4 aa = *(const float4*)(att + dc);
            float4 ab = *(const float4*)(att + dc + 4);
            v0 = fmaf(aa.x, leaky(xa.x + ra.x), v0);
            v0 = fmaf(aa.y, leaky(xa.y + ra.y), v0);
            v0 = fmaf(aa.z, leaky(xa.z + ra.z), v0);
            v0 = fmaf(aa.w, leaky(xa.w + ra.w), v0);
            v1 = fmaf(ab.x, leaky(xb.x + rb.x), v1);
            v1 = fmaf(ab.y, leaky(xb.y + rb.y), v1);
            v1 = fmaf(ab.z, leaky(xb.z + rb.z), v1);
            v1 = fmaf(ab.w, leaky(xb.w + rb.w), v1);
        }
        float w = (lane < nv) ? expf(v0 + v1) : 0.f;
        z += w;
        w_lds[wid][lane] = w;
        s_lds[wid][lane] = s;
        for (int e = 0; e < nv; e += 4) {
            float4 w4 = *(const float4*)&w_lds[wid][e];
            int4   s4 = *(const int4*)&s_lds[wid][e];
            float2 l0 = *(const float2*)(xl + (size_t)s4.x * D + lane2);
            float2 l1 = *(const float2*)(xl + (size_t)s4.y * D + lane2);
            float2 l2 = *(const float2*)(xl + (size_t)s4.z * D + lane2);
            float2 l3 = *(const float2*)(xl + (size_t)s4.w * D + lane2);
            acc.x = fmaf(w4.x, l0.x, acc.x); acc.y = fmaf(w4.x, l0.y, acc.y);
            acc.x = fmaf(w4.y, l1.x, acc.x); acc.y = fmaf(w4.y, l1.y, acc.y);
            acc.x = fmaf(w4.z, l2.x, acc.x); acc.y = fmaf(w4.z, l2.y, acc.y);
            acc.x = fmaf(w4.w, l3.x, acc.x); acc.y = fmaf(w4.w, l3.y, acc.y);
        }
    }
#pragma unroll
    for (int off = 32; off; off >>= 1) z += __shfl_xor(z, off);
    float inv = 1.f / z;
    float2 bv = *(const float2*)(bias + lane2);
    float2 o = { leaky(acc.x * inv + bv.x), leaky(acc.y * inv + bv.y) };

    const float* W1p = W1 + (size_t)t * D * D + lane2;
    float2 m = { 0.f, 0.f };
#pragma unroll 8
    for (int dp = 0; dp < 64; ++dp) {
        float fx = __shfl(o.x, dp);
        float fy = __shfl(o.y, dp);
        float2 wa = *(const float2*)(W1p + (size_t)(2 * dp) * D);
        float2 wb = *(const float2*)(W1p + (size_t)(2 * dp + 1) * D);
        m.x = fmaf(fx, wa.x, m.x); m.y = fmaf(fx, wa.y, m.y);
        m.x = fmaf(fy, wb.x, m.x); m.y = fmaf(fy, wb.y, m.y);
    }
    red[wid][lane] = m;
    __syncthreads();
    if (wid == 0) {
        float2 s0 = red[0][lane], s1 = red[1][lane], s2 = red[2][lane], s3 = red[3][lane];
        float2 s = { s0.x + s1.x + s2.x + s3.x, s0.y + s1.y + s2.y + s3.y };
        *(float2*)(partials + (size_t)blockIdx.x * D + lane2) = s;
    }
}

__device__ __forceinline__ float final8_body(const float* __restrict__ partials,
                                             const float* __restrict__ b1,
                                             const float* __restrict__ W2,
                                             float red[64][16]) {
    int tid = threadIdx.x;
    int rg = tid >> 4;
    int cl = tid & 15;
    int c = blockIdx.x * 16 + cl;
    float s = 0.f;
    for (int r = rg; r < NB_M; r += 64) s += partials[(size_t)r * D + c];
    red[rg][cl] = s;
    __syncthreads();
    if (tid < 128) {
        int cc = tid & 15, seg = tid >> 4;
        float t2 = red[seg * 8][cc];
        for (int m = 1; m < 8; ++m) t2 += red[seg * 8 + m][cc];
        red[seg * 8][cc] = t2;
    }
    __syncthreads();
    if (tid < 16) {
        float tot = 0.f;
        for (int m = 0; m < 8; ++m) tot += red[m * 8][tid];
        float h1 = fmaxf(tot + b1[blockIdx.x * 16 + tid], 0.f);
        red[0][tid] = h1 * W2[blockIdx.x * 16 + tid];
    }
    __syncthreads();
    float o = 0.f;
    if (tid == 0)
        for (int m = 0; m < 16; ++m) o += red[0][m];
    __syncthreads();
    return o;
}

// ================= pipeline kernels =================

__global__ __launch_bounds__(256) void k_hist(const int* __restrict__ dstA,
                                              int* __restrict__ cnt) {
    int base = (blockIdx.x * 256 + threadIdx.x) * 4;
    if (base >= EG) return;
    if (base + 4 <= E) {
        int4 d4 = *(const int4*)(dstA + base);
        atomicAdd(&cnt[d4.x], 1);
        atomicAdd(&cnt[d4.y], 1);
        atomicAdd(&cnt[d4.z], 1);
        atomicAdd(&cnt[d4.w], 1);
    } else {
        for (int kk = 0; kk < 4; ++kk) {
            int i = base + kk;
            if (i < EG) {
                int t = (i < E) ? dstA[i] : i - E;
                atomicAdd(&cnt[t], 1);
            }
        }
    }
}

__global__ __launch_bounds__(256) void k_scan(const int* __restrict__ cnt,
                                              int* __restrict__ rowptr,
                                              int* __restrict__ cursor) {
    __shared__ int ssum[256];
    scan_body(cnt, rowptr, cursor, ssum);
}

// pergene (blocks 0..1249) + bucket (blocks 1250..1489) + out zero
__global__ __launch_bounds__(256) void k_fuseA(const float* __restrict__ x,
                                               const float* __restrict__ Win,
                                               const float* __restrict__ bin,
                                               float* __restrict__ h,
                                               const int* __restrict__ srcA,
                                               const int* __restrict__ dstA,
                                               int* __restrict__ cursor,
                                               int* __restrict__ ssrc,
                                               float* __restrict__ outz) {
    if (blockIdx.x == 0 && threadIdx.x == 0) *outz = 0.f;
    if (blockIdx.x < NB_PG) {
        pergene_body(x, Win, bin, h);
    } else {
        int base = ((blockIdx.x - NB_PG) * 256 + threadIdx.x) * 4;
        if (base >= EG) return;
        if (base + 4 <= E) {
            int4 s4 = *(const int4*)(srcA + base);
            int4 d4 = *(const int4*)(dstA + base);
            int p;
            p = atomicAdd(&cursor[d4.x], 1); ssrc[p] = s4.x;
            p = atomicAdd(&cursor[d4.y], 1); ssrc[p] = s4.y;
            p = atomicAdd(&cursor[d4.z], 1); ssrc[p] = s4.z;
            p = atomicAdd(&cursor[d4.w], 1); ssrc[p] = s4.w;
        } else {
            for (int kk = 0; kk < 4; ++kk) {
                int i = base + kk;
                if (i < EG) {
                    int s, t;
                    if (i < E) { s = srcA[i]; t = dstA[i]; }
                    else { s = i - E; t = s; }
                    int p = atomicAdd(&cursor[t], 1);
                    ssrc[p] = s;
                }
            }
        }
    }
}

__global__ __launch_bounds__(256) void k_xlxr(const float* __restrict__ h,
                                              const float* __restrict__ Wl,
                                              const float* __restrict__ bl,
                                              const float* __restrict__ Wr,
                                              const float* __restrict__ br,
                                              float* __restrict__ xl,
                                              float* __restrict__ xr) {
    xlxr_body(blockIdx.x, h, Wl, bl, Wr, br, xl, xr);
}

__global__ __launch_bounds__(256) void k_aggmlp(const int* __restrict__ rowptr,
                                                const int* __restrict__ ssrc,
                                                const float* __restrict__ xl,
                                                const float* __restrict__ xr,
                                                const float* __restrict__ att,
                                                const float* __restrict__ bias,
                                                const float* __restrict__ W1,
                                                float* __restrict__ partials) {
    __shared__ float w_lds[4][64];
    __shared__ int   s_lds[4][64];
    __shared__ float2 red[4][64];
    aggmlp_body(rowptr, ssrc, xl, xr, att, bias, W1, partials, w_lds, s_lds, red);
}

__global__ __launch_bounds__(1024) void k_final8(const float* __restrict__ partials,
                                                 const float* __restrict__ b1,
                                                 const float* __restrict__ W2,
                                                 const float* __restrict__ b2,
                                                 float* __restrict__ out) {
    __shared__ float red[64][16];
    float o = final8_body(partials, b1, W2, red);
    if (threadIdx.x == 0) {
        if (blockIdx.x == 0) o += b2[0];
        atomicAdd(out, o);
    }
}

// ================= attribution rep-kernels (idempotent / throwaway) =================

__global__ __launch_bounds__(256) void k_pg_rep(const float* __restrict__ x,
                                                const float* __restrict__ Win,
                                                const float* __restrict__ bin,
                                                float* __restrict__ h) {
    for (int r = 0; r < 14; ++r) pergene_body(x, Win, bin, h);
}

__global__ __launch_bounds__(256) void k_xlxr_rep(const float* __restrict__ h,
                                                  const float* __restrict__ Wl,
                                                  const float* __restrict__ bl,
                                                  const float* __restrict__ Wr,
                                                  const float* __restrict__ br,
                                                  float* __restrict__ xl,
                                                  float* __restrict__ xr) {
    for (int r = 0; r < 48; ++r) xlxr_body(blockIdx.x, h, Wl, bl, Wr, br, xl, xr);
}

__global__ __launch_bounds__(256) void k_scan_rep(const int* __restrict__ cnt,
                                                  int* __restrict__ rowptr,
                                                  int* __restrict__ cursor) {
    __shared__ int ssum[256];
    for (int r = 0; r < 96; ++r) {
        __syncthreads();
        scan_body(cnt, rowptr, cursor, ssum);
    }
}

__global__ __launch_bounds__(256) void k_aggmlp_rep(const int* __restrict__ rowptr,
                                                    const int* __restrict__ ssrc,
                                                    const float* __restrict__ xl,
                                                    const float* __restrict__ xr,
                                                    const float* __restrict__ att,
                                                    const float* __restrict__ bias,
                                                    const float* __restrict__ W1,
                                                    float* __restrict__ partials) {
    __shared__ float w_lds[4][64];
    __shared__ int   s_lds[4][64];
    __shared__ float2 red[4][64];
    for (int r = 0; r < 3; ++r) {
        aggmlp_body(rowptr, ssrc, xl, xr, att, bias, W1, partials, w_lds, s_lds, red);
        __syncthreads();
    }
}

__global__ __launch_bounds__(1024) void k_final8_rep(const float* __restrict__ partials,
                                                     const float* __restrict__ b1,
                                                     const float* __restrict__ W2,
                                                     float* __restrict__ junk) {
    __shared__ float red[64][16];
    for (int r = 0; r < 96; ++r) {
        float o = final8_body(partials, b1, W2, red);
        if (threadIdx.x == 0) junk[blockIdx.x] = o;   // never read
        __syncthreads();
    }
}

extern "C" void kernel_launch(void* const* d_in, const int* in_sizes, int n_in,
                              void* d_out, int out_size, void* d_ws, size_t ws_size,
                              hipStream_t stream) {
    const float* x    = (const float*)d_in[0];
    const int*   ei   = (const int*)d_in[1];
    const float* Win  = (const float*)d_in[2];
    const float* bin  = (const float*)d_in[3];
    const float* Wl   = (const float*)d_in[4];
    const float* bl   = (const float*)d_in[5];
    const float* Wr   = (const float*)d_in[6];
    const float* br   = (const float*)d_in[7];
    const float* att  = (const float*)d_in[8];
    const float* bias = (const float*)d_in[9];
    const float* W1   = (const float*)d_in[10];
    const float* b1   = (const float*)d_in[11];
    const float* W2   = (const float*)d_in[12];
    const float* b2   = (const float*)d_in[13];
    float* out = (float*)d_out;

    float* ws       = (float*)d_ws;
    float* h        = ws;                 // GD
    float* xl       = h  + GD;            // GD
    float* xr       = xl + GD;            // GD
    float* partials = xr + GD;            // NB_M*D
    int*   ssrc     = (int*)(partials + (size_t)NB_M * D);  // EG
    int*   cnt      = ssrc + EG;          // G
    int*   rowptr   = cnt + G;            // G+1
    int*   cursor   = rowptr + G + 1;     // G
    float* junk     = (float*)(cursor + G);  // 8

    const int* srcA = ei;
    const int* dstA = ei + E;

    hipMemsetAsync(cnt, 0, G * sizeof(int), stream);
    k_hist<<<NB_H, 256, 0, stream>>>(dstA, cnt);
    k_scan<<<1, 256, 0, stream>>>(cnt, rowptr, cursor);
    k_fuseA<<<NB_PG + NB_H, 256, 0, stream>>>(x, Win, bin, h, srcA, dstA, cursor, ssrc, out);
    k_xlxr<<<NBX, 256, 0, stream>>>(h, Wl, bl, Wr, br, xl, xr);
    k_aggmlp<<<NB_M, 256, 0, stream>>>(rowptr, ssrc, xl, xr, att, bias, W1, partials);
    k_final8<<<8, 1024, 0, stream>>>(partials, b1, W2, b2, out);

    // ---- ATTRIBUTION reps (after output is final; idempotent / throwaway) ----
    k_pg_rep<<<NB_PG, 256, 0, stream>>>(x, Win, bin, h);
    k_xlxr_rep<<<NBX, 256, 0, stream>>>(h, Wl, bl, Wr, br, xl, xr);
    k_scan_rep<<<1, 256, 0, stream>>>(cnt, rowptr, cursor);
    k_aggmlp_rep<<<NB_M, 256, 0, stream>>>(rowptr, ssrc, xl, xr, att, bias, W1, partials);
    k_final8_rep<<<8, 1024, 0, stream>>>(partials, b1, W2, junk);
}

// Round 15
// 172.227 us; speedup vs baseline: 13.3442x; 13.3442x over previous
//
#include <hip/hip_runtime.h>
#include <math.h>

#define G 5000
#define IN 64
#define D 128
#define E 240000
#define EG (E + G)
#define SLOPE 0.2f
#define GD (G * D)
#define CAP 128          // fixed bucket capacity per destination (deg ~ Poisson(48)+1)
#define NB_M 1250        // aggmlp blocks (4 dests each)
#define NB_PG 1250       // pergene blocks (4 genes each)
#define NB_H 240         // bucket blocks (61440 int4 units >= 61250)

__device__ __forceinline__ float leaky(float v) { return v >= 0.f ? v : SLOPE * v; }

// ---------------- K_A: {pergene + xlxr} (blocks 0..1249) + bucket (blocks 1250..1489) ----------------
// pergene wave for gene g ends holding h[g] across lanes (o.x/o.y = cols 2l/2l+1);
// xl/xr = h @ W{l,r} + b computed in-register via shfl broadcast. h buffer eliminated.
// bucket: fixed-cap CSR — ssrc[t*CAP + atomicAdd(&cnt[t],1)] = s (no hist/scan needed).
__global__ __launch_bounds__(256) void k_fuseA(const float* __restrict__ x,
                                               const float* __restrict__ Win,
                                               const float* __restrict__ bin,
                                               const float* __restrict__ Wl,
                                               const float* __restrict__ bl,
                                               const float* __restrict__ Wr,
                                               const float* __restrict__ br,
                                               float* __restrict__ xl,
                                               float* __restrict__ xr,
                                               const int* __restrict__ srcA,
                                               const int* __restrict__ dstA,
                                               int* __restrict__ cnt,
                                               int* __restrict__ ssrc,
                                               float* __restrict__ outz) {
    if (blockIdx.x == 0 && threadIdx.x == 0) *outz = 0.f;   // consumed only by k_final8 (stream-ordered)
    if (blockIdx.x < NB_PG) {
        // ---- per-gene linear + relu (round-2 exact body) ----
        int g = (blockIdx.x * 256 + threadIdx.x) >> 6;
        int lane = threadIdx.x & 63;
        if (g >= G) return;
        float xv = x[g * IN + lane];
        const float* W = Win + (size_t)g * IN * D + lane * 2;
        float2 acc = *(const float2*)(bin + g * D + lane * 2);
#pragma unroll
        for (int i = 0; i < IN; ++i) {
            float xi = __shfl(xv, i);
            float2 w2 = *(const float2*)(W + (size_t)i * D);
            acc.x = fmaf(xi, w2.x, acc.x);
            acc.y = fmaf(xi, w2.y, acc.y);
        }
        float2 o = { fmaxf(acc.x, 0.f), fmaxf(acc.y, 0.f) };   // h[g][2l], h[g][2l+1]
        // ---- fused xlxr: lane owns cols (2l, 2l+1) of xl[g], xr[g] ----
        int d2 = lane * 2;
        float2 al = *(const float2*)(bl + d2);
        float2 ar = *(const float2*)(br + d2);
#pragma unroll 8
        for (int kp = 0; kp < 64; ++kp) {
            float hx = __shfl(o.x, kp);                         // h[g][2kp]
            float hy = __shfl(o.y, kp);                         // h[g][2kp+1]
            float2 wl0 = *(const float2*)(Wl + (2 * kp) * D + d2);
            float2 wl1 = *(const float2*)(Wl + (2 * kp + 1) * D + d2);
            float2 wr0 = *(const float2*)(Wr + (2 * kp) * D + d2);
            float2 wr1 = *(const float2*)(Wr + (2 * kp + 1) * D + d2);
            al.x = fmaf(hx, wl0.x, al.x); al.y = fmaf(hx, wl0.y, al.y);
            al.x = fmaf(hy, wl1.x, al.x); al.y = fmaf(hy, wl1.y, al.y);
            ar.x = fmaf(hx, wr0.x, ar.x); ar.y = fmaf(hx, wr0.y, ar.y);
            ar.x = fmaf(hy, wr1.x, ar.x); ar.y = fmaf(hy, wr1.y, ar.y);
        }
        *(float2*)(xl + (size_t)g * D + d2) = al;
        *(float2*)(xr + (size_t)g * D + d2) = ar;
    } else {
        // ---- bucket (int4 reads, fixed-cap) ----
        int base = ((blockIdx.x - NB_PG) * 256 + threadIdx.x) * 4;
        if (base >= EG) return;
        if (base + 4 <= E) {
            int4 s4 = *(const int4*)(srcA + base);
            int4 d4 = *(const int4*)(dstA + base);
            int p;
            p = atomicAdd(&cnt[d4.x], 1); if (p < CAP) ssrc[d4.x * CAP + p] = s4.x;
            p = atomicAdd(&cnt[d4.y], 1); if (p < CAP) ssrc[d4.y * CAP + p] = s4.y;
            p = atomicAdd(&cnt[d4.z], 1); if (p < CAP) ssrc[d4.z * CAP + p] = s4.z;
            p = atomicAdd(&cnt[d4.w], 1); if (p < CAP) ssrc[d4.w * CAP + p] = s4.w;
        } else {
            for (int kk = 0; kk < 4; ++kk) {
                int i = base + kk;
                if (i < EG) {
                    int s, t;
                    if (i < E) { s = srcA[i]; t = dstA[i]; }
                    else { s = i - E; t = s; }
                    int p = atomicAdd(&cnt[t], 1);
                    if (p < CAP) ssrc[t * CAP + p] = s;
                }
            }
        }
    }
}

// ---------------- K_AGGMLP: agg (round-12 body, fixed-cap CSR) fused with W1 GEMV slab ----------------
__global__ __launch_bounds__(256) void k_aggmlp(const int* __restrict__ cnt,
                                                const int* __restrict__ ssrc,
                                                const float* __restrict__ xl,
                                                const float* __restrict__ xr,
                                                const float* __restrict__ att,
                                                const float* __restrict__ bias,
                                                const float* __restrict__ W1,
                                                float* __restrict__ partials) {
    int wid = threadIdx.x >> 6;
    int lane = threadIdx.x & 63;
    int t = __builtin_amdgcn_readfirstlane(blockIdx.x * 4 + wid);   // wave-uniform
    __shared__ float w_lds[4][64];
    __shared__ int   s_lds[4][64];
    __shared__ float2 red[4][64];
    const float* xrt = xr + (size_t)t * D;
    int lane2 = lane * 2;
    int deg = cnt[t]; if (deg > CAP) deg = CAP;    // uniform (self-loop => deg >= 1)
    const int* srow = ssrc + t * CAP;
    float2 acc = { 0.f, 0.f };
    float z = 0.f;
    for (int base = 0; base < deg; base += 64) {
        int nv = deg - base; if (nv > 64) nv = 64;
        int mye = base + lane;
        int s = srow[mye < deg ? mye : deg - 1];
        // phase 1: per-lane full-D logit (no cross-lane ops)
        const float* xls = xl + (size_t)s * D;
        float v0 = 0.f, v1 = 0.f;
#pragma unroll
        for (int dc = 0; dc < D; dc += 8) {
            float4 xa = *(const float4*)(xls + dc);
            float4 xb = *(const float4*)(xls + dc + 4);
            float4 ra = *(const float4*)(xrt + dc);
            float4 rb = *(const float4*)(xrt + dc + 4);
            float4 aa = *(const float4*)(att + dc);
            float4 ab = *(const float4*)(att + dc + 4);
            v0 = fmaf(aa.x, leaky(xa.x + ra.x), v0);
            v0 = fmaf(aa.y, leaky(xa.y + ra.y), v0);
            v0 = fmaf(aa.z, leaky(xa.z + ra.z), v0);
            v0 = fmaf(aa.w, leaky(xa.w + ra.w), v0);
            v1 = fmaf(ab.x, leaky(xb.x + rb.x), v1);
            v1 = fmaf(ab.y, leaky(xb.y + rb.y), v1);
            v1 = fmaf(ab.z, leaky(xb.z + rb.z), v1);
            v1 = fmaf(ab.w, leaky(xb.w + rb.w), v1);
        }
        float w = (lane < nv) ? expf(v0 + v1) : 0.f;
        z += w;
        w_lds[wid][lane] = w;     // same-wave write->read: lockstep
        s_lds[wid][lane] = s;
        // phase 2: column-major weighted aggregate (uniform LDS broadcast reads)
        for (int e = 0; e < nv; e += 4) {
            float4 w4 = *(const float4*)&w_lds[wid][e];
            int4   s4 = *(const int4*)&s_lds[wid][e];
            float2 l0 = *(const float2*)(xl + (size_t)s4.x * D + lane2);
            float2 l1 = *(const float2*)(xl + (size_t)s4.y * D + lane2);
            float2 l2 = *(const float2*)(xl + (size_t)s4.z * D + lane2);
            float2 l3 = *(const float2*)(xl + (size_t)s4.w * D + lane2);
            acc.x = fmaf(w4.x, l0.x, acc.x); acc.y = fmaf(w4.x, l0.y, acc.y);
            acc.x = fmaf(w4.y, l1.x, acc.x); acc.y = fmaf(w4.y, l1.y, acc.y);
            acc.x = fmaf(w4.z, l2.x, acc.x); acc.y = fmaf(w4.z, l2.y, acc.y);
            acc.x = fmaf(w4.w, l3.x, acc.x); acc.y = fmaf(w4.w, l3.y, acc.y);
        }
    }
#pragma unroll
    for (int off = 32; off; off >>= 1) z += __shfl_xor(z, off);
    float inv = 1.f / z;
    float2 bv = *(const float2*)(bias + lane2);
    float2 o = { leaky(acc.x * inv + bv.x), leaky(acc.y * inv + bv.y) };   // f[t]

    // fused MLP1 slab: rows t*128 .. t*128+127 of W1, f_t broadcast from regs
    const float* W1p = W1 + (size_t)t * D * D + lane2;
    float2 m = { 0.f, 0.f };
#pragma unroll 8
    for (int dp = 0; dp < 64; ++dp) {
        float fx = __shfl(o.x, dp);
        float fy = __shfl(o.y, dp);
        float2 wa = *(const float2*)(W1p + (size_t)(2 * dp) * D);
        float2 wb = *(const float2*)(W1p + (size_t)(2 * dp + 1) * D);
        m.x = fmaf(fx, wa.x, m.x); m.y = fmaf(fx, wa.y, m.y);
        m.x = fmaf(fy, wb.x, m.x); m.y = fmaf(fy, wb.y, m.y);
    }
    red[wid][lane] = m;
    __syncthreads();
    if (wid == 0) {
        float2 s0 = red[0][lane], s1 = red[1][lane], s2 = red[2][lane], s3 = red[3][lane];
        float2 s = { s0.x + s1.x + s2.x + s3.x, s0.y + s1.y + s2.y + s3.y };
        *(float2*)(partials + (size_t)blockIdx.x * D + lane2) = s;
    }
}

// ---------------- K6: 8-block column-sliced reduce + relu + dot W2 (round-10 exact) ----------------
__global__ __launch_bounds__(1024) void k_final8(const float* __restrict__ partials,
                                                 const float* __restrict__ b1,
                                                 const float* __restrict__ W2,
                                                 const float* __restrict__ b2,
                                                 float* __restrict__ out) {
    int tid = threadIdx.x;
    int rg = tid >> 4;
    int cl = tid & 15;
    int c = blockIdx.x * 16 + cl;
    float s = 0.f;
    for (int r = rg; r < NB_M; r += 64) s += partials[(size_t)r * D + c];
    __shared__ float red[64][16];
    red[rg][cl] = s;
    __syncthreads();
    if (tid < 128) {
        int cc = tid & 15, seg = tid >> 4;
        float t2 = red[seg * 8][cc];
        for (int m = 1; m < 8; ++m) t2 += red[seg * 8 + m][cc];
        red[seg * 8][cc] = t2;
    }
    __syncthreads();
    if (tid < 16) {
        float tot = 0.f;
        for (int m = 0; m < 8; ++m) tot += red[m * 8][tid];
        float h1 = fmaxf(tot + b1[blockIdx.x * 16 + tid], 0.f);
        red[0][tid] = h1 * W2[blockIdx.x * 16 + tid];
    }
    __syncthreads();
    if (tid == 0) {
        float o = 0.f;
        for (int m = 0; m < 16; ++m) o += red[0][m];
        if (blockIdx.x == 0) o += b2[0];
        atomicAdd(out, o);
    }
}

extern "C" void kernel_launch(void* const* d_in, const int* in_sizes, int n_in,
                              void* d_out, int out_size, void* d_ws, size_t ws_size,
                              hipStream_t stream) {
    const float* x    = (const float*)d_in[0];
    const int*   ei   = (const int*)d_in[1];
    const float* Win  = (const float*)d_in[2];
    const float* bin  = (const float*)d_in[3];
    const float* Wl   = (const float*)d_in[4];
    const float* bl   = (const float*)d_in[5];
    const float* Wr   = (const float*)d_in[6];
    const float* br   = (const float*)d_in[7];
    const float* att  = (const float*)d_in[8];
    const float* bias = (const float*)d_in[9];
    const float* W1   = (const float*)d_in[10];
    const float* b1   = (const float*)d_in[11];
    const float* W2   = (const float*)d_in[12];
    const float* b2   = (const float*)d_in[13];
    float* out = (float*)d_out;

    float* ws       = (float*)d_ws;
    float* xl       = ws;                 // GD
    float* xr       = xl + GD;            // GD
    float* partials = xr + GD;            // NB_M*D
    int*   ssrc     = (int*)(partials + (size_t)NB_M * D);  // G*CAP
    int*   cnt      = ssrc + (size_t)G * CAP;               // G

    const int* srcA = ei;
    const int* dstA = ei + E;

    hipMemsetAsync(cnt, 0, G * sizeof(int), stream);
    k_fuseA<<<NB_PG + NB_H, 256, 0, stream>>>(x, Win, bin, Wl, bl, Wr, br, xl, xr,
                                              srcA, dstA, cnt, ssrc, out);
    k_aggmlp<<<NB_M, 256, 0, stream>>>(cnt, ssrc, xl, xr, att, bias, W1, partials);
    k_final8<<<8, 1024, 0, stream>>>(partials, b1, W2, b2, out);
}

// Round 16
// 154.846 us; speedup vs baseline: 14.8421x; 1.1122x over previous
//
#include <hip/hip_runtime.h>
#include <math.h>

#define G 5000
#define IN 64
#define D 128
#define E 240000
#define EG (E + G)
#define SLOPE 0.2f
#define GD (G * D)
#define CAP 128          // fixed bucket capacity per destination (deg ~ Poisson(48)+1)
#define NB_M 1250        // aggmlp blocks (4 dests each)
#define NB_PG 1250       // pergene blocks (4 genes each)
#define NB_H 240         // bucket blocks (61440 int4 units >= 61250)
#define NB_X 1250        // xlxr blocks (4 genes each)

__device__ __forceinline__ float leaky(float v) { return v >= 0.f ? v : SLOPE * v; }

// ---------------- K_A: pergene (blocks 0..1249, round-2 exact body) + bucket (fixed-cap) ----------------
__global__ __launch_bounds__(256) void k_fuseA(const float* __restrict__ x,
                                               const float* __restrict__ Win,
                                               const float* __restrict__ bin,
                                               float* __restrict__ h,
                                               const int* __restrict__ srcA,
                                               const int* __restrict__ dstA,
                                               int* __restrict__ cnt,
                                               int* __restrict__ ssrc,
                                               float* __restrict__ outz) {
    if (blockIdx.x == 0 && threadIdx.x == 0) *outz = 0.f;   // consumed only by k_final8 (stream-ordered)
    if (blockIdx.x < NB_PG) {
        int g = (blockIdx.x * 256 + threadIdx.x) >> 6;
        int lane = threadIdx.x & 63;
        if (g >= G) return;
        float xv = x[g * IN + lane];
        const float* W = Win + (size_t)g * IN * D + lane * 2;
        float2 acc = *(const float2*)(bin + g * D + lane * 2);
#pragma unroll
        for (int i = 0; i < IN; ++i) {
            float xi = __shfl(xv, i);
            float2 w2 = *(const float2*)(W + (size_t)i * D);
            acc.x = fmaf(xi, w2.x, acc.x);
            acc.y = fmaf(xi, w2.y, acc.y);
        }
        float2 o = { fmaxf(acc.x, 0.f), fmaxf(acc.y, 0.f) };
        *(float2*)(h + g * D + lane * 2) = o;
    } else {
        // bucket (int4 reads, fixed-cap CSR): ssrc[t*CAP + atomicAdd(&cnt[t],1)] = s
        int base = ((blockIdx.x - NB_PG) * 256 + threadIdx.x) * 4;
        if (base >= EG) return;
        if (base + 4 <= E) {
            int4 s4 = *(const int4*)(srcA + base);
            int4 d4 = *(const int4*)(dstA + base);
            int p;
            p = atomicAdd(&cnt[d4.x], 1); if (p < CAP) ssrc[d4.x * CAP + p] = s4.x;
            p = atomicAdd(&cnt[d4.y], 1); if (p < CAP) ssrc[d4.y * CAP + p] = s4.y;
            p = atomicAdd(&cnt[d4.z], 1); if (p < CAP) ssrc[d4.z * CAP + p] = s4.z;
            p = atomicAdd(&cnt[d4.w], 1); if (p < CAP) ssrc[d4.w * CAP + p] = s4.w;
        } else {
            for (int kk = 0; kk < 4; ++kk) {
                int i = base + kk;
                if (i < EG) {
                    int s, t;
                    if (i < E) { s = srcA[i]; t = dstA[i]; }
                    else { s = i - E; t = s; }
                    int p = atomicAdd(&cnt[t], 1);
                    if (p < CAP) ssrc[t * CAP + p] = s;
                }
            }
        }
    }
}

// ---------------- K_XLXR3: column-per-thread, 4 genes/block, 1250 blocks ----------------
// tid < 128: column `tid` of xl; tid >= 128: column `tid-128` of xr.
// h rows are thread-uniform addresses -> scalar (s_load) L2-hit loads; W columns coalesced.
__global__ __launch_bounds__(256) void k_xlxr3(const float* __restrict__ h,
                                               const float* __restrict__ Wl,
                                               const float* __restrict__ bl,
                                               const float* __restrict__ Wr,
                                               const float* __restrict__ br,
                                               float* __restrict__ xl,
                                               float* __restrict__ xr) {
    int g0 = blockIdx.x * 4;
    int tid = threadIdx.x;
    int half = tid >> 7;          // 0 -> l, 1 -> r
    int col = tid & 127;
    const float* W = half ? Wr : Wl;
    const float* bb = half ? br : bl;
    float* o = half ? xr : xl;
    const float* h0p = h + (size_t)(g0 + 0) * D;
    const float* h1p = h + (size_t)(g0 + 1) * D;
    const float* h2p = h + (size_t)(g0 + 2) * D;
    const float* h3p = h + (size_t)(g0 + 3) * D;
    float b = bb[col];
    float acc0 = b, acc1 = b, acc2 = b, acc3 = b;
#pragma unroll 8
    for (int k4 = 0; k4 < 32; ++k4) {
        int k = k4 * 4;
        float4 hv0 = *(const float4*)(h0p + k);   // uniform -> s_load_dwordx4
        float4 hv1 = *(const float4*)(h1p + k);
        float4 hv2 = *(const float4*)(h2p + k);
        float4 hv3 = *(const float4*)(h3p + k);
        float w0 = W[(size_t)(k + 0) * D + col];  // coalesced across lanes
        float w1 = W[(size_t)(k + 1) * D + col];
        float w2 = W[(size_t)(k + 2) * D + col];
        float w3 = W[(size_t)(k + 3) * D + col];
        acc0 = fmaf(hv0.x, w0, acc0); acc0 = fmaf(hv0.y, w1, acc0);
        acc0 = fmaf(hv0.z, w2, acc0); acc0 = fmaf(hv0.w, w3, acc0);
        acc1 = fmaf(hv1.x, w0, acc1); acc1 = fmaf(hv1.y, w1, acc1);
        acc1 = fmaf(hv1.z, w2, acc1); acc1 = fmaf(hv1.w, w3, acc1);
        acc2 = fmaf(hv2.x, w0, acc2); acc2 = fmaf(hv2.y, w1, acc2);
        acc2 = fmaf(hv2.z, w2, acc2); acc2 = fmaf(hv2.w, w3, acc2);
        acc3 = fmaf(hv3.x, w0, acc3); acc3 = fmaf(hv3.y, w1, acc3);
        acc3 = fmaf(hv3.z, w2, acc3); acc3 = fmaf(hv3.w, w3, acc3);
    }
    o[(size_t)(g0 + 0) * D + col] = acc0;
    o[(size_t)(g0 + 1) * D + col] = acc1;
    o[(size_t)(g0 + 2) * D + col] = acc2;
    o[(size_t)(g0 + 3) * D + col] = acc3;
}

// ---------------- K_AGGMLP: agg (fixed-cap CSR) fused with W1 GEMV slab (round-15 exact) ----------------
__global__ __launch_bounds__(256) void k_aggmlp(const int* __restrict__ cnt,
                                                const int* __restrict__ ssrc,
                                                const float* __restrict__ xl,
                                                const float* __restrict__ xr,
                                                const float* __restrict__ att,
                                                const float* __restrict__ bias,
                                                const float* __restrict__ W1,
                                                float* __restrict__ partials) {
    int wid = threadIdx.x >> 6;
    int lane = threadIdx.x & 63;
    int t = __builtin_amdgcn_readfirstlane(blockIdx.x * 4 + wid);   // wave-uniform
    __shared__ float w_lds[4][64];
    __shared__ int   s_lds[4][64];
    __shared__ float2 red[4][64];
    const float* xrt = xr + (size_t)t * D;
    int lane2 = lane * 2;
    int deg = cnt[t]; if (deg > CAP) deg = CAP;    // self-loop => deg >= 1
    const int* srow = ssrc + t * CAP;
    float2 acc = { 0.f, 0.f };
    float z = 0.f;
    for (int base = 0; base < deg; base += 64) {
        int nv = deg - base; if (nv > 64) nv = 64;
        int mye = base + lane;
        int s = srow[mye < deg ? mye : deg - 1];
        // phase 1: per-lane full-D logit (no cross-lane ops)
        const float* xls = xl + (size_t)s * D;
        float v0 = 0.f, v1 = 0.f;
#pragma unroll
        for (int dc = 0; dc < D; dc += 8) {
            float4 xa = *(const float4*)(xls + dc);
            float4 xb = *(const float4*)(xls + dc + 4);
            float4 ra = *(const float4*)(xrt + dc);
            float4 rb = *(const float4*)(xrt + dc + 4);
            float4 aa = *(const float4*)(att + dc);
            float4 ab = *(const float4*)(att + dc + 4);
            v0 = fmaf(aa.x, leaky(xa.x + ra.x), v0);
            v0 = fmaf(aa.y, leaky(xa.y + ra.y), v0);
            v0 = fmaf(aa.z, leaky(xa.z + ra.z), v0);
            v0 = fmaf(aa.w, leaky(xa.w + ra.w), v0);
            v1 = fmaf(ab.x, leaky(xb.x + rb.x), v1);
            v1 = fmaf(ab.y, leaky(xb.y + rb.y), v1);
            v1 = fmaf(ab.z, leaky(xb.z + rb.z), v1);
            v1 = fmaf(ab.w, leaky(xb.w + rb.w), v1);
        }
        float w = (lane < nv) ? expf(v0 + v1) : 0.f;
        z += w;
        w_lds[wid][lane] = w;     // same-wave write->read: lockstep
        s_lds[wid][lane] = s;
        // phase 2: column-major weighted aggregate (uniform LDS broadcast reads)
        for (int e = 0; e < nv; e += 4) {
            float4 w4 = *(const float4*)&w_lds[wid][e];
            int4   s4 = *(const int4*)&s_lds[wid][e];
            float2 l0 = *(const float2*)(xl + (size_t)s4.x * D + lane2);
            float2 l1 = *(const float2*)(xl + (size_t)s4.y * D + lane2);
            float2 l2 = *(const float2*)(xl + (size_t)s4.z * D + lane2);
            float2 l3 = *(const float2*)(xl + (size_t)s4.w * D + lane2);
            acc.x = fmaf(w4.x, l0.x, acc.x); acc.y = fmaf(w4.x, l0.y, acc.y);
            acc.x = fmaf(w4.y, l1.x, acc.x); acc.y = fmaf(w4.y, l1.y, acc.y);
            acc.x = fmaf(w4.z, l2.x, acc.x); acc.y = fmaf(w4.z, l2.y, acc.y);
            acc.x = fmaf(w4.w, l3.x, acc.x); acc.y = fmaf(w4.w, l3.y, acc.y);
        }
    }
#pragma unroll
    for (int off = 32; off; off >>= 1) z += __shfl_xor(z, off);
    float inv = 1.f / z;
    float2 bv = *(const float2*)(bias + lane2);
    float2 o = { leaky(acc.x * inv + bv.x), leaky(acc.y * inv + bv.y) };   // f[t]

    // fused MLP1 slab: rows t*128 .. t*128+127 of W1, f_t broadcast from regs
    const float* W1p = W1 + (size_t)t * D * D + lane2;
    float2 m = { 0.f, 0.f };
#pragma unroll 8
    for (int dp = 0; dp < 64; ++dp) {
        float fx = __shfl(o.x, dp);
        float fy = __shfl(o.y, dp);
        float2 wa = *(const float2*)(W1p + (size_t)(2 * dp) * D);
        float2 wb = *(const float2*)(W1p + (size_t)(2 * dp + 1) * D);
        m.x = fmaf(fx, wa.x, m.x); m.y = fmaf(fx, wa.y, m.y);
        m.x = fmaf(fy, wb.x, m.x); m.y = fmaf(fy, wb.y, m.y);
    }
    red[wid][lane] = m;
    __syncthreads();
    if (wid == 0) {
        float2 s0 = red[0][lane], s1 = red[1][lane], s2 = red[2][lane], s3 = red[3][lane];
        float2 s = { s0.x + s1.x + s2.x + s3.x, s0.y + s1.y + s2.y + s3.y };
        *(float2*)(partials + (size_t)blockIdx.x * D + lane2) = s;
    }
}

// ---------------- K6: 8-block column-sliced reduce + relu + dot W2 (round-10 exact) ----------------
__global__ __launch_bounds__(1024) void k_final8(const float* __restrict__ partials,
                                                 const float* __restrict__ b1,
                                                 const float* __restrict__ W2,
                                                 const float* __restrict__ b2,
                                                 float* __restrict__ out) {
    int tid = threadIdx.x;
    int rg = tid >> 4;
    int cl = tid & 15;
    int c = blockIdx.x * 16 + cl;
    float s = 0.f;
    for (int r = rg; r < NB_M; r += 64) s += partials[(size_t)r * D + c];
    __shared__ float red[64][16];
    red[rg][cl] = s;
    __syncthreads();
    if (tid < 128) {
        int cc = tid & 15, seg = tid >> 4;
        float t2 = red[seg * 8][cc];
        for (int m = 1; m < 8; ++m) t2 += red[seg * 8 + m][cc];
        red[seg * 8][cc] = t2;
    }
    __syncthreads();
    if (tid < 16) {
        float tot = 0.f;
        for (int m = 0; m < 8; ++m) tot += red[m * 8][tid];
        float h1 = fmaxf(tot + b1[blockIdx.x * 16 + tid], 0.f);
        red[0][tid] = h1 * W2[blockIdx.x * 16 + tid];
    }
    __syncthreads();
    if (tid == 0) {
        float o = 0.f;
        for (int m = 0; m < 16; ++m) o += red[0][m];
        if (blockIdx.x == 0) o += b2[0];
        atomicAdd(out, o);
    }
}

extern "C" void kernel_launch(void* const* d_in, const int* in_sizes, int n_in,
                              void* d_out, int out_size, void* d_ws, size_t ws_size,
                              hipStream_t stream) {
    const float* x    = (const float*)d_in[0];
    const int*   ei   = (const int*)d_in[1];
    const float* Win  = (const float*)d_in[2];
    const float* bin  = (const float*)d_in[3];
    const float* Wl   = (const float*)d_in[4];
    const float* bl   = (const float*)d_in[5];
    const float* Wr   = (const float*)d_in[6];
    const float* br   = (const float*)d_in[7];
    const float* att  = (const float*)d_in[8];
    const float* bias = (const float*)d_in[9];
    const float* W1   = (const float*)d_in[10];
    const float* b1   = (const float*)d_in[11];
    const float* W2   = (const float*)d_in[12];
    const float* b2   = (const float*)d_in[13];
    float* out = (float*)d_out;

    float* ws       = (float*)d_ws;
    float* h        = ws;                 // GD
    float* xl       = h  + GD;            // GD
    float* xr       = xl + GD;            // GD
    float* partials = xr + GD;            // NB_M*D
    int*   ssrc     = (int*)(partials + (size_t)NB_M * D);  // G*CAP
    int*   cnt      = ssrc + (size_t)G * CAP;               // G

    const int* srcA = ei;
    const int* dstA = ei + E;

    hipMemsetAsync(cnt, 0, G * sizeof(int), stream);
    k_fuseA<<<NB_PG + NB_H, 256, 0, stream>>>(x, Win, bin, h, srcA, dstA, cnt, ssrc, out);
    k_xlxr3<<<NB_X, 256, 0, stream>>>(h, Wl, bl, Wr, br, xl, xr);
    k_aggmlp<<<NB_M, 256, 0, stream>>>(cnt, ssrc, xl, xr, att, bias, W1, partials);
    k_final8<<<8, 1024, 0, stream>>>(partials, b1, W2, b2, out);
}